// Round 5
// baseline (377.887 us; speedup 1.0000x reference)
//
#include <hip/hip_runtime.h>
#include <stdint.h>

// Problem: KS=3, ST=2, PAD=1, H=W=28, C=768, NH=12, hh=ww=14, dh=64.
//
// R8: R7 post-mortem -- persistent row-blocks DOUBLED HBM fetch (99->213 MB,
// L2/L3 locality lost) and the unroll-1 quad loop serialized latency chains;
// OccupancyPercent is a gfx94x-formula fallback and pins at ~28% even when
// the grid must be fully resident -> ignore it. R8 returns to R6's proven
// short-lived quad-major blocks (best FETCH + best time) and attacks the
// remaining latency serialization:
//   - 384-thread block = 2 horizontally adjacent quads (per-wave code
//     identical to R6): 2x waves per dispatch slot, windows overlap in L1.
//   - attn via LDS: R6 did <=81 scalar global attn loads per thread,
//     16x redundant (16 threads/head read the same values) and interleaved
//     with the FMA chain (load-9 -> fma-36 -> load-9 ... serialization).
//     Now the block stages its 6 (h,w) attn chunks into LDS (31 KB,
//     p-padded to 12 floats so each 9-float run is 16B-aligned ->
//     ds_read_b128), 18 coalesced global loads/thread issued up front
//     alongside the 25 tap loads; compute reads broadcast LDS.
//   - __launch_bounds__(384,3): VGPR cap 170 so all 25 float4 tap loads
//     can be in flight (R6's 68 VGPR batched them).
//   - nontemporal float4 stores: out (150 MB) is write-once -- keep it out
//     of L2/L3 so the 203 MB of inputs stays cache-resident.
//
// Quad formulation (verified R6/R7): quad (qy,qx) -> output pixels
// (y0..y0+1, x0..x0+1), y0=2qy, x0=2qx, one shared 5x5 float4 tap window
// (rows y0-1..y0+3, cols x0-1..x0+3); 9 fixed attn runs:
//   P(0,0): p=4@(qy,qx)
//   P(0,1): p=5@(qy,qx); p=3@(qy,qx+1) if qx<13
//   P(1,0): p=7@(qy,qx); p=1@(qy+1,qx) if qy<13
//   P(1,1): p=8@(qy,qx); p=6@(qy,qx+1) if qx<13;
//           p=2@(qy+1,qx) if qy<13; p=0@(qy+1,qx+1) if both
#define HOUT 28
#define HH   14
#define NHEADS 12
#define CC   768
#define NPIX (HOUT * HOUT)   // 784
#define NQ   (HH * HH)       // 196 quads per image
#define AHW  (NHEADS * 81)   // 972 floats per (h,w) in global attn

// LDS attn layout: [chunk 6][head 12][p 9][q 12 padded]  (floats)
#define ALDS_Q  12
#define ALDS_P  (9 * ALDS_Q)        // 108 floats per head
#define ALDS_HW (NHEADS * ALDS_P)   // 1296 floats per (h,w) chunk
#define ALDS_TOTAL (6 * ALDS_HW)    // 7776 floats = 31104 B

typedef float vfloat4 __attribute__((ext_vector_type(4)));

// acc += sum_{qh,qw} ap[qh*3+qw] * v[IO+qh][JO+qw]; ap is 16B-aligned LDS.
template<int IO, int JO>
__device__ __forceinline__ void fma9L(float4& acc,
                                      const float* ap,
                                      const float4 (&v)[5][5])
{
    const float4 q0 = *(const float4*)(ap + 0);
    const float4 q1 = *(const float4*)(ap + 4);
    const float  a8 = ap[8];
    const float a[9] = {q0.x, q0.y, q0.z, q0.w, q1.x, q1.y, q1.z, q1.w, a8};
    #pragma unroll
    for (int qh = 0; qh < 3; ++qh)
        #pragma unroll
        for (int qw = 0; qw < 3; ++qw) {
            const float  aa = a[qh * 3 + qw];
            const float4 u  = v[IO + qh][JO + qw];
            acc.x = fmaf(aa, u.x, acc.x);
            acc.y = fmaf(aa, u.y, acc.y);
            acc.z = fmaf(aa, u.z, acc.z);
            acc.w = fmaf(aa, u.w, acc.w);
        }
}

__global__ __launch_bounds__(384, 3)
void UnfoldMatmulFold_kernel(const float* __restrict__ vv,
                             const float* __restrict__ attn,
                             float* __restrict__ out)
{
    // XCD-aware decode: (id & 7) == (b & 7). j in [0,784):
    // bgrp = j/98, pr = j%98 -> qy = pr/7, qxp = pr%7.
    // Block covers quads (qy, 2*qxp) and (qy, 2*qxp+1) of image b.
    const unsigned id   = blockIdx.x;           // 0..6271
    const unsigned xcd  = id & 7u;
    const unsigned j    = id >> 3;              // 0..783
    const unsigned bgrp = j / 98u;              // 0..7
    const unsigned pr   = j - bgrp * 98u;       // 0..97
    const int b   = (int)((bgrp << 3) | xcd);
    const int qy  = (int)(pr / 7u);             // 0..13
    const int qxp = (int)(pr - (unsigned)qy * 7u); // 0..6
    const int w0  = qxp << 1;                   // first quad's qx
    const int y0  = qy << 1;

    const int tid  = threadIdx.x;               // 0..383
    const int qloc = tid >= 192;                // 0 = quad A, 1 = quad B
    const int t    = tid - (qloc ? 192 : 0);    // 0..191
    const int c4   = t << 2;                    // 4 channels per thread
    const int n    = t >> 4;                    // head
    const int qx   = w0 + qloc;                 // this thread's quad
    const int x0   = qx << 1;

    __shared__ __align__(16) float att_lds[ALDS_TOTAL];

    // ---- Phase 1: 25 independent float4 tap loads (issued up front). ----
    const float* vb = vv + (size_t)b * (NPIX * CC) + c4;
    float4 v[5][5];
    bool rowok[5];
    #pragma unroll
    for (int i = 0; i < 5; ++i) {
        const int r  = y0 - 1 + i;
        rowok[i]     = ((unsigned)r < HOUT);
        const int rs = rowok[i] ? r : y0;
        const float* vrow = vb + (size_t)(rs * HOUT) * CC;
        #pragma unroll
        for (int jj = 0; jj < 5; ++jj) {
            const int cpos = x0 - 1 + jj;
            const int cs   = ((unsigned)cpos < HOUT) ? cpos : x0;
            v[i][jj] = *(const float4*)(vrow + (size_t)cs * CC);
        }
    }

    // ---- Phase 2: cooperative attn staging into LDS. ----
    // 6 chunks: (qy+dy, w0+dw), dy in {0,1}, dw in {0,1,2}; clamped address
    // (invalid chunks are never read: hasX/hasY guards below).
    {
        const float* abase = attn + (size_t)b * (NQ * AHW);
        #pragma unroll
        for (int c = 0; c < 6; ++c) {
            const int dy = c / 3, dw = c - dy * 3;
            int h = qy + dy; if (h > 13) h = 13;
            int w = w0 + dw; if (w > 13) w = 13;
            const float* g = abase + (size_t)(h * HH + w) * AHW;
            float* l = att_lds + c * ALDS_HW;
            #pragma unroll
            for (int k = 0; k < 3; ++k) {
                const int inner = tid + k * 384;
                if (inner < AHW) {
                    const int nn = inner / 81;
                    const int r  = inner - nn * 81;
                    const int p  = r / 9;
                    const int q  = r - p * 9;
                    l[nn * ALDS_P + p * ALDS_Q + q] = g[inner];
                }
            }
        }
    }

    // Zero OOB taps (vv zero-padding). Row part block-uniform.
    #pragma unroll
    for (int i = 0; i < 5; ++i) {
        #pragma unroll
        for (int jj = 0; jj < 5; ++jj) {
            const bool cv = (unsigned)(x0 - 1 + jj) < HOUT;
            if (!(rowok[i] && cv)) {
                v[i][jj].x = 0.f; v[i][jj].y = 0.f;
                v[i][jj].z = 0.f; v[i][jj].w = 0.f;
            }
        }
    }

    __syncthreads();

    // ---- Phase 3: FMA chain, attn from broadcast LDS. ----
    // Chunk index for this quad: a00=(0,qloc) a01=(0,qloc+1)
    //                            a10=(1,qloc) a11=(1,qloc+1)
    const float* A00 = att_lds + (0 + qloc    ) * ALDS_HW + n * ALDS_P;
    const float* A01 = att_lds + (0 + qloc + 1) * ALDS_HW + n * ALDS_P;
    const float* A10 = att_lds + (3 + qloc    ) * ALDS_HW + n * ALDS_P;
    const float* A11 = att_lds + (3 + qloc + 1) * ALDS_HW + n * ALDS_P;

    const bool hasX = (qx < 13);
    const bool hasY = (qy < 13);

    const size_t ob = (((size_t)b * HOUT + y0) * HOUT + x0) * CC + c4;
    float4 acc;

    // P(0,0)
    acc.x = acc.y = acc.z = acc.w = 0.f;
    fma9L<0, 0>(acc, A00 + 4 * ALDS_Q, v);
    __builtin_nontemporal_store(*(vfloat4*)&acc, (vfloat4*)&out[ob]);

    // P(0,1)
    acc.x = acc.y = acc.z = acc.w = 0.f;
    fma9L<0, 0>(acc, A00 + 5 * ALDS_Q, v);
    if (hasX) fma9L<0, 2>(acc, A01 + 3 * ALDS_Q, v);
    __builtin_nontemporal_store(*(vfloat4*)&acc, (vfloat4*)&out[ob + CC]);

    // P(1,0)
    acc.x = acc.y = acc.z = acc.w = 0.f;
    fma9L<0, 0>(acc, A00 + 7 * ALDS_Q, v);
    if (hasY) fma9L<2, 0>(acc, A10 + 1 * ALDS_Q, v);
    __builtin_nontemporal_store(*(vfloat4*)&acc, (vfloat4*)&out[ob + HOUT * CC]);

    // P(1,1)
    acc.x = acc.y = acc.z = acc.w = 0.f;
    fma9L<0, 0>(acc, A00 + 8 * ALDS_Q, v);
    if (hasX) fma9L<0, 2>(acc, A01 + 6 * ALDS_Q, v);
    if (hasY) fma9L<2, 0>(acc, A10 + 2 * ALDS_Q, v);
    if (hasX && hasY) fma9L<2, 2>(acc, A11 + 0 * ALDS_Q, v);
    __builtin_nontemporal_store(*(vfloat4*)&acc, (vfloat4*)&out[ob + (HOUT + 1) * CC]);
}

extern "C" void kernel_launch(void* const* d_in, const int* in_sizes, int n_in,
                              void* d_out, int out_size, void* d_ws, size_t ws_size,
                              hipStream_t stream) {
    const float* vv   = (const float*)d_in[0];
    const float* attn = (const float*)d_in[1];
    float* out        = (float*)d_out;

    const int B = in_sizes[0] / (NPIX * CC);   // elements -> 64
    dim3 grid((unsigned)(B * 98));             // 6272 blocks, 2 quads each
    UnfoldMatmulFold_kernel<<<grid, 384, 0, stream>>>(vv, attn, out);
}

// Round 6
// 337.451 us; speedup vs baseline: 1.1198x; 1.1198x over previous
//
#include <hip/hip_runtime.h>
#include <stdint.h>

// Problem: KS=3, ST=2, PAD=1, H=W=28, C=768, NH=12, hh=ww=14, dh=64.
//
// R9 = R6 (best: 149us/dispatch) + ONE change: vectorized attn-run loads.
// R6's per-wave VMEM: 25 tap b128 + 81 attn dword + 4 store b128 = 110
// instructions, with the 81 attn loads interleaved serially with FMA groups
// (load-9 -> wait -> fma-36 -> ...). Each 9-float run is contiguous ->
// load as 2x dwordx4 + 1 dword (dword-aligned 16B global loads are legal on
// gfx9+; aligned(4) ext-vector makes clang emit global_load_dwordx4).
// Per-wave VMEM drops to 25 + 27 + 4 = 56 (-49%).
// R8 lesson folded in: attn redundancy across the 16 threads/head is FREE
// (same-address -> coalesced, L1-broadcast; FETCH identical) -- what costs
// is instruction count + wait chains, so cut those, no LDS, no barrier.
//
// Quad formulation (verified R6/R7/R8): block computes 2x2 output pixels
// (y0,x0)=(2qy,2qx) sharing one 5x5 float4 tap window; contributing
// (kh,kw) combos = 9 fixed attn runs, compile-time p and tap offsets:
//   P(0,0): p=4@(qy,qx)
//   P(0,1): p=5@(qy,qx); p=3@(qy,qx+1) if qx<13
//   P(1,0): p=7@(qy,qx); p=1@(qy+1,qx) if qy<13
//   P(1,1): p=8@(qy,qx); p=6@(qy,qx+1) if qx<13;
//           p=2@(qy+1,qx) if qy<13; p=0@(qy+1,qx+1) if both
// vv zero-padding handled by zeroing OOB taps (block-uniform conditions).
#define HOUT 28
#define HH   14
#define NHEADS 12
#define CC   768
#define NPIX (HOUT * HOUT)   // 784
#define NQ   (HH * HH)       // 196 quads per image
#define AHW  (NHEADS * 81)   // 972 floats per (h,w)

// 16B vector with only 4B alignment guarantee: attn runs start at
// (n*81 + p*9) floats from a 16B-aligned base -> dword-aligned only.
typedef float f4u __attribute__((ext_vector_type(4), aligned(4)));

// acc += sum_{k=0..8} ap[k] * v[IO + k/3][JO + k%3]
// ap: contiguous 9 floats in global, loaded as dwordx4 + dwordx4 + dword.
template<int IO, int JO>
__device__ __forceinline__ void fma9G(float4& acc,
                                      const float* __restrict__ ap,
                                      const float4 (&v)[5][5])
{
    const f4u  q0 = *(const f4u*)(ap + 0);   // a[0..3]
    const f4u  q1 = *(const f4u*)(ap + 4);   // a[4..7]
    const float a8 = ap[8];
    const float a[9] = {q0.x, q0.y, q0.z, q0.w, q1.x, q1.y, q1.z, q1.w, a8};
    #pragma unroll
    for (int qh = 0; qh < 3; ++qh)
        #pragma unroll
        for (int qw = 0; qw < 3; ++qw) {
            const float  aa = a[qh * 3 + qw];
            const float4 u  = v[IO + qh][JO + qw];
            acc.x = fmaf(aa, u.x, acc.x);
            acc.y = fmaf(aa, u.y, acc.y);
            acc.z = fmaf(aa, u.z, acc.z);
            acc.w = fmaf(aa, u.w, acc.w);
        }
}

__global__ __launch_bounds__(192)
void UnfoldMatmulFold_kernel(const float* __restrict__ vv,
                             const float* __restrict__ attn,
                             float* __restrict__ out)
{
    // XCD-aware swizzle: (id & 7) == (b & 7) keeps one image's working set
    // resident in a single XCD's L2 (heuristic only).
    const unsigned id   = blockIdx.x;
    const unsigned xcd  = id & 7u;
    const unsigned j    = id >> 3;
    const unsigned bgrp = j / NQ;          // 0..7
    const unsigned q    = j - bgrp * NQ;   // 0..195
    const int b  = (int)((bgrp << 3) | xcd);
    const int qy = (int)(q / HH);
    const int qx = (int)(q - (unsigned)qy * HH);
    const int y0 = qy << 1;
    const int x0 = qx << 1;

    const int tid = threadIdx.x;     // 0..191
    const int c4  = tid << 2;        // 4 channels per thread
    const int n   = tid >> 4;        // head (64 ch = 16 threads per head)

    const float* vb = vv + (size_t)b * (NPIX * CC) + c4;

    // ---- Phase 1: 5x5 tap window, all 25 float4 loads issued up front. ----
    float4 v[5][5];
    #pragma unroll
    for (int i = 0; i < 5; ++i) {
        const int r  = y0 - 1 + i;
        const int rs = ((unsigned)r < HOUT) ? r : y0;     // safe addr
        const float* vrow = vb + (size_t)(rs * HOUT) * CC;
        #pragma unroll
        for (int jj = 0; jj < 5; ++jj) {
            const int cpos = x0 - 1 + jj;
            const int cs   = ((unsigned)cpos < HOUT) ? cpos : x0;
            v[i][jj] = *(const float4*)(vrow + (size_t)cs * CC);
        }
    }

    // Zero OOB taps (vv zero-padding). Conditions are block-uniform.
    #pragma unroll
    for (int i = 0; i < 5; ++i) {
        const bool rv = (unsigned)(y0 - 1 + i) < HOUT;
        #pragma unroll
        for (int jj = 0; jj < 5; ++jj) {
            const bool cv = (unsigned)(x0 - 1 + jj) < HOUT;
            if (!(rv && cv)) {
                v[i][jj].x = 0.f; v[i][jj].y = 0.f;
                v[i][jj].z = 0.f; v[i][jj].w = 0.f;
            }
        }
    }

    // ---- Phase 2: the 9 attn runs (each 9 contiguous floats). ----
    const float* ab = attn + (size_t)b * (NQ * AHW) + n * 81;
    const size_t hw00 = (size_t)(qy * HH + qx) * AHW;
    const float* a00 = ab + hw00;                              // (qy,  qx  )
    const float* a01 = ab + hw00 + (size_t)AHW;                // (qy,  qx+1)
    const float* a10 = ab + hw00 + (size_t)(HH * AHW);         // (qy+1,qx  )
    const float* a11 = ab + hw00 + (size_t)((HH + 1) * AHW);   // (qy+1,qx+1)

    const bool hasX = (qx < 13);
    const bool hasY = (qy < 13);

    const size_t ob = (((size_t)b * HOUT + y0) * HOUT + x0) * CC + c4;
    float4 acc;

    // P(0,0)
    acc.x = acc.y = acc.z = acc.w = 0.f;
    fma9G<0, 0>(acc, a00 + 4 * 9, v);
    *(float4*)&out[ob] = acc;

    // P(0,1)
    acc.x = acc.y = acc.z = acc.w = 0.f;
    fma9G<0, 0>(acc, a00 + 5 * 9, v);
    if (hasX) fma9G<0, 2>(acc, a01 + 3 * 9, v);
    *(float4*)&out[ob + CC] = acc;

    // P(1,0)
    acc.x = acc.y = acc.z = acc.w = 0.f;
    fma9G<0, 0>(acc, a00 + 7 * 9, v);
    if (hasY) fma9G<2, 0>(acc, a10 + 1 * 9, v);
    *(float4*)&out[ob + HOUT * CC] = acc;

    // P(1,1)
    acc.x = acc.y = acc.z = acc.w = 0.f;
    fma9G<0, 0>(acc, a00 + 8 * 9, v);
    if (hasX) fma9G<0, 2>(acc, a01 + 6 * 9, v);
    if (hasY) fma9G<2, 0>(acc, a10 + 2 * 9, v);
    if (hasX && hasY) fma9G<2, 2>(acc, a11 + 0 * 9, v);
    *(float4*)&out[ob + (HOUT + 1) * CC] = acc;
}

extern "C" void kernel_launch(void* const* d_in, const int* in_sizes, int n_in,
                              void* d_out, int out_size, void* d_ws, size_t ws_size,
                              hipStream_t stream) {
    const float* vv   = (const float*)d_in[0];
    const float* attn = (const float*)d_in[1];
    float* out        = (float*)d_out;

    const int B = in_sizes[0] / (NPIX * CC);   // elements -> 64
    dim3 grid((unsigned)(B * NQ));             // 12544 blocks, quad-major
    UnfoldMatmulFold_kernel<<<grid, 192, 0, stream>>>(vv, attn, out);
}